// Round 2
// baseline (2767.794 us; speedup 1.0000x reference)
//
#include <hip/hip_runtime.h>

#define NPB 32  // nodes per block in k_conv (256 threads, 8 lanes/node)

__device__ __forceinline__ unsigned f2key(float x){
  unsigned b = __float_as_uint(x);
  return (b & 0x80000000u) ? ~b : (b | 0x80000000u);
}
__device__ __forceinline__ float key2f(unsigned k){
  return (k & 0x80000000u) ? __uint_as_float(k ^ 0x80000000u) : __uint_as_float(~k);
}

// ---------------- CSR build ----------------
// NOTE: harness delivers integer inputs as int32 (edge_index int64 -> const int*).

__global__ void k_deg(const int* __restrict__ ei, int* __restrict__ deg, int E, int n){
  int e = blockIdx.x*blockDim.x + threadIdx.x;
  if (e < E){
    int d = ei[E + e];
    if ((unsigned)d < (unsigned)n) atomicAdd(&deg[d], 1);  // guard: never fault
  }
}

__global__ __launch_bounds__(1024) void k_scan1(const int* __restrict__ deg, int* __restrict__ offs,
                                                int* __restrict__ bsum, int n){
  __shared__ int tmp[1024];
  int tid = threadIdx.x;
  int gid = blockIdx.x*1024 + tid;
  int v = (gid < n) ? deg[gid] : 0;
  tmp[tid] = v;
  __syncthreads();
  for (int o=1;o<1024;o<<=1){
    int t = (tid>=o) ? tmp[tid-o] : 0;
    __syncthreads();
    if (tid>=o) tmp[tid] += t;
    __syncthreads();
  }
  int inc = tmp[tid];
  if (gid < n) offs[gid] = inc - v;   // exclusive within chunk
  if (tid == 1023) bsum[blockIdx.x] = inc;
}

__global__ void k_scan2(const int* __restrict__ bsum, int* __restrict__ bpre, int nb){
  if (threadIdx.x==0 && blockIdx.x==0){
    int acc=0;
    for (int i=0;i<nb;i++){ bpre[i]=acc; acc+=bsum[i]; }
  }
}

__global__ void k_scan3(int* __restrict__ offs, const int* __restrict__ bpre, int* __restrict__ cursor,
                        float* __restrict__ invdeg, const int* __restrict__ deg, int n, int E){
  int gid = blockIdx.x*blockDim.x + threadIdx.x;
  if (gid < n){
    int o = offs[gid] + bpre[gid>>10];
    offs[gid]=o; cursor[gid]=o;
    int d = deg[gid];
    invdeg[gid] = 1.0f / (float)(d>0?d:1);
  }
  if (gid==0) offs[n] = E;
}

__global__ void k_fill(const int* __restrict__ ei, int* __restrict__ cursor,
                       int* __restrict__ csr, int E, int n){
  int e = blockIdx.x*blockDim.x + threadIdx.x;
  if (e < E){
    int s = ei[e];
    int d = ei[E + e];
    if ((unsigned)s < (unsigned)n && (unsigned)d < (unsigned)n){
      int pos = atomicAdd(&cursor[d], 1);
      if ((unsigned)pos < (unsigned)E) csr[pos] = s;
    }
  }
}

// ---------------- proj_in: gather x[4] + (avg@A + x@B) + row softmax ----------------

__global__ __launch_bounds__(256) void k_in(const float* __restrict__ x, float* __restrict__ hout,
    const int* __restrict__ offs, const int* __restrict__ csr, const float* __restrict__ invdeg,
    const float* __restrict__ A, const float* __restrict__ B, int n){
  __shared__ float sA[128], sB[128];
  int tid = threadIdx.x;
  if (tid < 128){ sA[tid]=A[tid]; sB[tid]=B[tid]; }
  __syncthreads();
  int node = blockIdx.x*256 + tid;
  if (node >= n) return;
  float4 s = {0,0,0,0};
  int b0=offs[node], e0=offs[node+1];
  for (int k=b0;k<e0;k++){
    int sid = csr[k];
    float4 v = ((const float4*)x)[sid];
    s.x+=v.x; s.y+=v.y; s.z+=v.z; s.w+=v.w;
  }
  float idg = invdeg[node];
  s.x*=idg; s.y*=idg; s.z*=idg; s.w*=idg;
  float4 xr = ((const float4*)x)[node];
  float z[32];
  #pragma unroll
  for (int j=0;j<32;j++){
    z[j] = s.x*sA[j] + s.y*sA[32+j] + s.z*sA[64+j] + s.w*sA[96+j]
         + xr.x*sB[j] + xr.y*sB[32+j] + xr.z*sB[64+j] + xr.w*sB[96+j];
  }
  float m = z[0];
  #pragma unroll
  for (int j=1;j<32;j++) m = fmaxf(m,z[j]);
  float sum=0.0f;
  #pragma unroll
  for (int j=0;j<32;j++){ z[j]=expf(z[j]-m); sum+=z[j]; }
  float r = 1.0f/sum;
  float4* op = (float4*)(hout + ((size_t)node<<5));
  #pragma unroll
  for (int q=0;q<8;q++){
    float4 t = {z[4*q]*r, z[4*q+1]*r, z[4*q+2]*r, z[4*q+3]*r};
    op[q]=t;
  }
}

// ---------------- conv round: gather h[32] + dual matmul + row softmax + colmax ----------------

__global__ __launch_bounds__(256) void k_conv(const float* __restrict__ hin, float* __restrict__ hout,
    const int* __restrict__ offs, const int* __restrict__ csr, const float* __restrict__ invdeg,
    const float* __restrict__ Wa, const float* __restrict__ Wb,
    unsigned* __restrict__ colmax, int n){
  __shared__ float sWa[1024], sWb[1024];
  __shared__ float sAv[NPB][33];
  __shared__ float sHr[NPB][33];
  int tid = threadIdx.x;
  ((float4*)sWa)[tid] = ((const float4*)Wa)[tid];
  ((float4*)sWb)[tid] = ((const float4*)Wb)[tid];
  int nl = tid>>3, sl = tid&7;
  int node = blockIdx.x*NPB + nl;
  bool valid = node < n;
  if (valid){
    float4 acc = {0,0,0,0}, acc2 = {0,0,0,0};
    int b0=offs[node], e0=offs[node+1];
    const float4* hbase = (const float4*)hin;
    int k=b0;
    for (; k+1<e0; k+=2){
      int s0=csr[k], s1=csr[k+1];
      float4 v0 = hbase[((size_t)s0<<3)+sl];
      float4 v1 = hbase[((size_t)s1<<3)+sl];
      acc.x+=v0.x; acc.y+=v0.y; acc.z+=v0.z; acc.w+=v0.w;
      acc2.x+=v1.x; acc2.y+=v1.y; acc2.z+=v1.z; acc2.w+=v1.w;
    }
    if (k<e0){
      float4 v = hbase[((size_t)csr[k]<<3)+sl];
      acc.x+=v.x; acc.y+=v.y; acc.z+=v.z; acc.w+=v.w;
    }
    acc.x+=acc2.x; acc.y+=acc2.y; acc.z+=acc2.z; acc.w+=acc2.w;
    float idg = invdeg[node];
    acc.x*=idg; acc.y*=idg; acc.z*=idg; acc.w*=idg;
    float4 hr = hbase[((size_t)node<<3)+sl];
    int c = sl*4;
    sAv[nl][c]=acc.x; sAv[nl][c+1]=acc.y; sAv[nl][c+2]=acc.z; sAv[nl][c+3]=acc.w;
    sHr[nl][c]=hr.x; sHr[nl][c+1]=hr.y; sHr[nl][c+2]=hr.z; sHr[nl][c+3]=hr.w;
  }
  __syncthreads();
  float4 z = {0,0,0,0};
  #pragma unroll
  for (int f=0; f<32; f++){
    float a = sAv[nl][f], hh = sHr[nl][f];
    float4 wa = ((const float4*)(sWa + f*32))[sl];
    float4 wb = ((const float4*)(sWb + f*32))[sl];
    z.x += a*wa.x + hh*wb.x;
    z.y += a*wa.y + hh*wb.y;
    z.z += a*wa.z + hh*wb.z;
    z.w += a*wa.w + hh*wb.w;
  }
  // row softmax across this node's 8 lanes (lanes of a node are contiguous in the wave)
  float m = fmaxf(fmaxf(z.x,z.y), fmaxf(z.z,z.w));
  m = fmaxf(m, __shfl_xor(m,1));
  m = fmaxf(m, __shfl_xor(m,2));
  m = fmaxf(m, __shfl_xor(m,4));
  float4 e;
  e.x=expf(z.x-m); e.y=expf(z.y-m); e.z=expf(z.z-m); e.w=expf(z.w-m);
  float ssum = e.x+e.y+e.z+e.w;
  ssum += __shfl_xor(ssum,1);
  ssum += __shfl_xor(ssum,2);
  ssum += __shfl_xor(ssum,4);
  float r = 1.0f/ssum;
  float4 p = { e.x*r, e.y*r, e.z*r, e.w*r };
  __syncthreads();  // done reading sAv/sHr for matmul; reuse sAv for colmax reduce
  if (valid){
    ((float4*)hout)[((size_t)node<<3)+sl] = p;
  }
  int c = sl*4;
  sAv[nl][c]   = valid ? p.x : 0.0f;
  sAv[nl][c+1] = valid ? p.y : 0.0f;
  sAv[nl][c+2] = valid ? p.z : 0.0f;
  sAv[nl][c+3] = valid ? p.w : 0.0f;
  __syncthreads();
  if (tid < 32){
    float mm = sAv[0][tid];
    #pragma unroll
    for (int nd=1; nd<NPB; nd++) mm = fmaxf(mm, sAv[nd][tid]);
    atomicMax(&colmax[tid], __float_as_uint(mm));  // values are positive -> bit compare valid
  }
}

// ---------------- column softmax: sum of exp ----------------

__global__ __launch_bounds__(256) void k_colsum(const float* __restrict__ htmp, const unsigned* __restrict__ cmaxb,
                                                float* __restrict__ csum, int n){
  __shared__ float part[32];
  int tid = threadIdx.x;
  if (tid<32) part[tid]=0.0f;
  __syncthreads();
  int sl = tid & 7;
  float4 cm;
  cm.x = __uint_as_float(cmaxb[sl*4]);
  cm.y = __uint_as_float(cmaxb[sl*4+1]);
  cm.z = __uint_as_float(cmaxb[sl*4+2]);
  cm.w = __uint_as_float(cmaxb[sl*4+3]);
  float4 ls = {0,0,0,0};
  int total = n*8;
  for (int u = blockIdx.x*blockDim.x + tid; u < total; u += gridDim.x*blockDim.x){
    float4 v = ((const float4*)htmp)[u];
    ls.x += expf(v.x - cm.x);
    ls.y += expf(v.y - cm.y);
    ls.z += expf(v.z - cm.z);
    ls.w += expf(v.w - cm.w);
  }
  for (int o=8;o<64;o<<=1){
    ls.x += __shfl_xor(ls.x,o);
    ls.y += __shfl_xor(ls.y,o);
    ls.z += __shfl_xor(ls.z,o);
    ls.w += __shfl_xor(ls.w,o);
  }
  if ((tid & 63) < 8){
    atomicAdd(&part[sl*4],   ls.x);
    atomicAdd(&part[sl*4+1], ls.y);
    atomicAdd(&part[sl*4+2], ls.z);
    atomicAdd(&part[sl*4+3], ls.w);
  }
  __syncthreads();
  if (tid<32) atomicAdd(&csum[tid], part[tid]);
}

__global__ __launch_bounds__(256) void k_norm(const float* __restrict__ htmp, float* __restrict__ hout,
                       const unsigned* __restrict__ cmaxb, const float* __restrict__ csum, int n){
  int tid = threadIdx.x;
  int sl = tid & 7;
  float4 cm, cs;
  cm.x = __uint_as_float(cmaxb[sl*4]);
  cm.y = __uint_as_float(cmaxb[sl*4+1]);
  cm.z = __uint_as_float(cmaxb[sl*4+2]);
  cm.w = __uint_as_float(cmaxb[sl*4+3]);
  cs.x = csum[sl*4]; cs.y = csum[sl*4+1]; cs.z = csum[sl*4+2]; cs.w = csum[sl*4+3];
  float4 rc = {1.0f/cs.x, 1.0f/cs.y, 1.0f/cs.z, 1.0f/cs.w};
  int total = n*8;
  for (int u = blockIdx.x*blockDim.x + tid; u < total; u += gridDim.x*blockDim.x){
    float4 v = ((const float4*)htmp)[u];
    float4 o;
    o.x = expf(v.x - cm.x) * rc.x;
    o.y = expf(v.y - cm.y) * rc.y;
    o.z = expf(v.z - cm.z) * rc.z;
    o.w = expf(v.w - cm.w) * rc.w;
    ((float4*)hout)[u] = o;
  }
}

// ---------------- output layer ----------------

__global__ __launch_bounds__(256) void k_out1(const float* __restrict__ h, const float* __restrict__ W,
    const float* __restrict__ bptr, float* __restrict__ z, unsigned* __restrict__ zmaxkey, int n){
  __shared__ float red[256];
  int tid = threadIdx.x;
  int node = blockIdx.x*256 + tid;
  float zz = -3.0e38f;
  if (node < n){
    float acc = bptr[0];
    const float4* hr = (const float4*)(h + ((size_t)node<<5));
    const float4* w4 = (const float4*)W;
    #pragma unroll
    for (int q=0;q<8;q++){
      float4 a=hr[q], b=w4[q];
      acc += a.x*b.x + a.y*b.y + a.z*b.z + a.w*b.w;
    }
    z[node]=acc; zz=acc;
  }
  red[tid]=zz; __syncthreads();
  for (int s=128;s>0;s>>=1){
    if (tid<s) red[tid]=fmaxf(red[tid],red[tid+s]);
    __syncthreads();
  }
  if (tid==0) atomicMax(zmaxkey, f2key(red[0]));
}

__global__ __launch_bounds__(256) void k_out2(const float* __restrict__ z, const unsigned* __restrict__ zmaxkey,
                                              float* __restrict__ zsum, int n){
  __shared__ float red[256];
  int tid = threadIdx.x;
  int node = blockIdx.x*256 + tid;
  float zmax = key2f(*zmaxkey);
  float v = (node<n) ? expf(z[node]-zmax) : 0.0f;
  red[tid]=v; __syncthreads();
  for (int s=128;s>0;s>>=1){
    if (tid<s) red[tid]+=red[tid+s];
    __syncthreads();
  }
  if (tid==0) atomicAdd(zsum, red[0]);
}

__global__ __launch_bounds__(256) void k_out3(const float* __restrict__ z, const unsigned* __restrict__ zmaxkey,
                                              const float* __restrict__ zsum, float* __restrict__ out, int n){
  int node = blockIdx.x*256 + threadIdx.x;
  if (node < n){
    float zmax = key2f(*zmaxkey);
    out[node] = expf(z[node]-zmax) / (*zsum);
  }
}

// ---------------- host launcher ----------------

extern "C" void kernel_launch(void* const* d_in, const int* in_sizes, int n_in,
                              void* d_out, int out_size, void* d_ws, size_t ws_size,
                              hipStream_t stream) {
  const float* x      = (const float*)d_in[0];
  const int*   ei     = (const int*)d_in[1];   // int64 in reference -> int32 on device per harness
  const float* A_in   = (const float*)d_in[2];
  const float* B_in   = (const float*)d_in[3];
  const float* A_conv = (const float*)d_in[4];
  const float* B_conv = (const float*)d_in[5];
  const float* W_out  = (const float*)d_in[6];
  const float* b_out  = (const float*)d_in[7];
  const int N = in_sizes[0] / 4;
  const int E = in_sizes[1] / 2;
  const int NROUNDS = 16;

  // workspace partition (16B aligned)
  char* w = (char*)d_ws;
  size_t o = 0;
  auto alloc = [&](size_t bytes)->char* {
    char* p = w + o;
    o = (o + bytes + 15) & ~(size_t)15;
    return p;
  };
  // ---- zero-init control region (contiguous, one memset) ----
  int*      deg     = (int*)     alloc((size_t)N*4);
  unsigned* colmax  = (unsigned*)alloc((size_t)NROUNDS*32*4);
  float*    colsum  = (float*)   alloc((size_t)NROUNDS*32*4);
  unsigned* zmaxkey = (unsigned*)alloc(4);
  float*    zsum    = (float*)   alloc(4);
  size_t ctrl_bytes = o;
  // ---- rest ----
  int*   offs   = (int*)  alloc((size_t)(N+1)*4);
  int*   cursor = (int*)  alloc((size_t)N*4);
  float* invdeg = (float*)alloc((size_t)N*4);
  int    nb     = (N + 1023) / 1024;
  int*   bsum   = (int*)  alloc((size_t)nb*4);
  int*   bpre   = (int*)  alloc((size_t)nb*4);
  int*   csr    = (int*)  alloc((size_t)E*4);
  float* hA     = (float*)alloc((size_t)N*32*4);
  float* hB     = (float*)alloc((size_t)N*32*4);
  float* zbuf   = (float*)hB;  // hB free after last k_norm (which writes hA)
  (void)ws_size; (void)n_in; (void)out_size;

  hipMemsetAsync(d_ws, 0, ctrl_bytes, stream);

  int gridE = (E + 255) / 256;
  int gridN = (N + 255) / 256;
  int gridC = (N + NPB - 1) / NPB;

  // CSR build
  k_deg  <<<gridE, 256, 0, stream>>>(ei, deg, E, N);
  k_scan1<<<nb, 1024, 0, stream>>>(deg, offs, bsum, N);
  k_scan2<<<1, 64, 0, stream>>>(bsum, bpre, nb);
  k_scan3<<<gridN, 256, 0, stream>>>(offs, bpre, cursor, invdeg, deg, N, E);
  k_fill <<<gridE, 256, 0, stream>>>(ei, cursor, csr, E, N);

  // proj_in
  k_in<<<gridN, 256, 0, stream>>>(x, hA, offs, csr, invdeg, A_in, B_in, N);

  // 16 conv rounds
  for (int r = 0; r < NROUNDS; r++){
    const float* Wa = A_conv + (size_t)r*32*32;
    const float* Wb = B_conv + (size_t)r*32*32;
    unsigned* cm = colmax + (size_t)r*32;
    float*    cs = colsum + (size_t)r*32;
    k_conv  <<<gridC, 256, 0, stream>>>(hA, hB, offs, csr, invdeg, Wa, Wb, cm, N);
    k_colsum<<<512, 256, 0, stream>>>(hB, cm, cs, N);
    k_norm  <<<gridC, 256, 0, stream>>>(hB, hA, cm, cs, N);
  }

  // output layer
  k_out1<<<gridN, 256, 0, stream>>>(hA, W_out, b_out, zbuf, zmaxkey, N);
  k_out2<<<gridN, 256, 0, stream>>>(zbuf, zmaxkey, zsum, N);
  k_out3<<<gridN, 256, 0, stream>>>(zbuf, zmaxkey, zsum, (float*)d_out, N);
}

// Round 3
// 2098.719 us; speedup vs baseline: 1.3188x; 1.3188x over previous
//
#include <hip/hip_runtime.h>

#define NPB 32   // nodes per block in k_conv (256 threads, 8 lanes/node)
#define NSEG 8
#define SEGSH 19 // segment = edge >> 19  (E=3.2M -> segments 0..6)

typedef float    f4 __attribute__((ext_vector_type(4)));
typedef _Float16 h4 __attribute__((ext_vector_type(4)));

__device__ __forceinline__ unsigned f2key(float x){
  unsigned b = __float_as_uint(x);
  return (b & 0x80000000u) ? ~b : (b | 0x80000000u);
}
__device__ __forceinline__ float key2f(unsigned k){
  return (k & 0x80000000u) ? __uint_as_float(k ^ 0x80000000u) : __uint_as_float(~k);
}

// ---------------- CSR build (8-way segmented counters to cut same-address atomic conflicts) ----------------

__global__ void k_deg(const int* __restrict__ ei, int* __restrict__ deg8, int E, int n){
  int e = blockIdx.x*blockDim.x + threadIdx.x;
  if (e < E){
    int d = ei[E + e];
    int seg = e >> SEGSH; if (seg > NSEG-1) seg = NSEG-1;
    if ((unsigned)d < (unsigned)n) atomicAdd(&deg8[seg*n + d], 1);
  }
}

__global__ __launch_bounds__(1024) void k_scan1(const int* __restrict__ deg8, int* __restrict__ offs,
                                                int* __restrict__ bsum, int n){
  __shared__ int tmp[1024];
  int tid = threadIdx.x;
  int gid = blockIdx.x*1024 + tid;
  int v = 0;
  if (gid < n){
    #pragma unroll
    for (int s=0;s<NSEG;s++) v += deg8[s*n + gid];
  }
  tmp[tid] = v;
  __syncthreads();
  for (int o=1;o<1024;o<<=1){
    int t = (tid>=o) ? tmp[tid-o] : 0;
    __syncthreads();
    if (tid>=o) tmp[tid] += t;
    __syncthreads();
  }
  int inc = tmp[tid];
  if (gid < n) offs[gid] = inc - v;   // exclusive within chunk
  if (tid == 1023) bsum[blockIdx.x] = inc;
}

__global__ void k_scan2(const int* __restrict__ bsum, int* __restrict__ bpre, int nb){
  if (threadIdx.x==0 && blockIdx.x==0){
    int acc=0;
    for (int i=0;i<nb;i++){ bpre[i]=acc; acc+=bsum[i]; }
  }
}

__global__ void k_scan3(int* __restrict__ offs, const int* __restrict__ bpre,
                        const int* __restrict__ deg8, int* __restrict__ cursor8,
                        float* __restrict__ invdeg, int n, int E){
  int gid = blockIdx.x*blockDim.x + threadIdx.x;
  if (gid < n){
    int base = offs[gid] + bpre[gid>>10];
    offs[gid] = base;
    int cum = base, dtot = 0;
    #pragma unroll
    for (int s=0;s<NSEG;s++){
      int d8 = deg8[s*n + gid];
      cursor8[s*n + gid] = cum;
      cum += d8; dtot += d8;
    }
    invdeg[gid] = 1.0f / (float)(dtot>0?dtot:1);
  }
  if (gid==0) offs[n] = E;
}

__global__ void k_fill(const int* __restrict__ ei, int* __restrict__ cursor8,
                       int* __restrict__ csr, int E, int n){
  int e = blockIdx.x*blockDim.x + threadIdx.x;
  if (e < E){
    int s = ei[e];
    int d = ei[E + e];
    int seg = e >> SEGSH; if (seg > NSEG-1) seg = NSEG-1;
    if ((unsigned)s < (unsigned)n && (unsigned)d < (unsigned)n){
      int pos = atomicAdd(&cursor8[seg*n + d], 1);
      if ((unsigned)pos < (unsigned)E) csr[pos] = s;
    }
  }
}

// ---------------- proj_in: gather x[4] + (avg@A + x@B) + row softmax -> u0 = p (fp16), rc0 = 1 ----------------

__global__ __launch_bounds__(256) void k_in(const float* __restrict__ x, _Float16* __restrict__ uout,
    const int* __restrict__ offs, const int* __restrict__ csr, const float* __restrict__ invdeg,
    const float* __restrict__ A, const float* __restrict__ B, int n){
  __shared__ float sA[128], sB[128];
  int tid = threadIdx.x;
  if (tid < 128){ sA[tid]=A[tid]; sB[tid]=B[tid]; }
  __syncthreads();
  int node = blockIdx.x*256 + tid;
  if (node >= n) return;
  float4 s = {0,0,0,0};
  int b0=offs[node], e0=offs[node+1];
  for (int k=b0;k<e0;k++){
    int sid = csr[k];
    float4 v = ((const float4*)x)[sid];
    s.x+=v.x; s.y+=v.y; s.z+=v.z; s.w+=v.w;
  }
  float idg = invdeg[node];
  s.x*=idg; s.y*=idg; s.z*=idg; s.w*=idg;
  float4 xr = ((const float4*)x)[node];
  float z[32];
  #pragma unroll
  for (int j=0;j<32;j++){
    z[j] = s.x*sA[j] + s.y*sA[32+j] + s.z*sA[64+j] + s.w*sA[96+j]
         + xr.x*sB[j] + xr.y*sB[32+j] + xr.z*sB[64+j] + xr.w*sB[96+j];
  }
  float m = z[0];
  #pragma unroll
  for (int j=1;j<32;j++) m = fmaxf(m,z[j]);
  float sum=0.0f;
  #pragma unroll
  for (int j=0;j<32;j++){ z[j]=expf(z[j]-m); sum+=z[j]; }
  float r = 1.0f/sum;
  h4* op = (h4*)uout + (size_t)node*8;
  #pragma unroll
  for (int q=0;q<8;q++){
    f4 t = { z[4*q]*r, z[4*q+1]*r, z[4*q+2]*r, z[4*q+3]*r };
    op[q] = __builtin_convertvector(t, h4);
  }
}

// ---------------- conv round: gather u (fp16) + dual matmul (rc folded into W) + row softmax
//                  -> write u' = exp(p) (fp16) + column-sum atomics. No colmax/norm passes needed:
//                  p in [0,1] so softmax_col(p) = exp(p)/sum(exp(p)) exactly. ----------------

__global__ __launch_bounds__(256) void k_conv(
    const _Float16* __restrict__ uin, _Float16* __restrict__ uout,
    const int* __restrict__ offs, const int* __restrict__ csr,
    const float* __restrict__ invdeg,
    const float* __restrict__ Wa, const float* __restrict__ Wb,
    const float* __restrict__ cs_prev, float* __restrict__ cs_next, int n){
  __shared__ float sWa[1024], sWb[1024];
  __shared__ float sAv[NPB][33], sOwn[NPB][33];
  int tid = threadIdx.x;
  float rcf = 1.0f;
  if (cs_prev) rcf = 1.0f / cs_prev[tid>>3];   // row f = tid/8 of the [32][32] weight
  ((f4*)sWa)[tid] = ((const f4*)Wa)[tid] * rcf;
  ((f4*)sWb)[tid] = ((const f4*)Wb)[tid] * rcf;
  int nl = tid>>3, sl = tid&7;
  int node = blockIdx.x*NPB + nl;
  bool valid = node < n;
  f4 acc = {0,0,0,0}, own = {0,0,0,0};
  if (valid){
    f4 acc2 = {0,0,0,0};
    int b0=offs[node], e0=offs[node+1];
    const h4* ub = (const h4*)uin;
    int k=b0;
    for (; k+1<e0; k+=2){
      int s0=csr[k], s1=csr[k+1];
      acc  += __builtin_convertvector(ub[(size_t)s0*8 + sl], f4);
      acc2 += __builtin_convertvector(ub[(size_t)s1*8 + sl], f4);
    }
    if (k<e0) acc += __builtin_convertvector(ub[(size_t)csr[k]*8 + sl], f4);
    acc += acc2;
    acc *= invdeg[node];
    own = __builtin_convertvector(ub[(size_t)node*8 + sl], f4);
  }
  int c = sl*4;
  sAv[nl][c]=acc[0]; sAv[nl][c+1]=acc[1]; sAv[nl][c+2]=acc[2]; sAv[nl][c+3]=acc[3];
  sOwn[nl][c]=own[0]; sOwn[nl][c+1]=own[1]; sOwn[nl][c+2]=own[2]; sOwn[nl][c+3]=own[3];
  __syncthreads();
  f4 z = {0,0,0,0};
  #pragma unroll
  for (int f=0; f<32; f++){
    float a = sAv[nl][f], o = sOwn[nl][f];
    f4 wa = ((const f4*)(sWa + f*32))[sl];
    f4 wb = ((const f4*)(sWb + f*32))[sl];
    z += a*wa + o*wb;
  }
  // row softmax across this node's 8 lanes
  float m = fmaxf(fmaxf(z[0],z[1]), fmaxf(z[2],z[3]));
  m = fmaxf(m, __shfl_xor(m,1));
  m = fmaxf(m, __shfl_xor(m,2));
  m = fmaxf(m, __shfl_xor(m,4));
  f4 ev = { expf(z[0]-m), expf(z[1]-m), expf(z[2]-m), expf(z[3]-m) };
  float ss = ev[0]+ev[1]+ev[2]+ev[3];
  ss += __shfl_xor(ss,1);
  ss += __shfl_xor(ss,2);
  ss += __shfl_xor(ss,4);
  float r = 1.0f/ss;
  f4 p = ev*r;                       // row-softmax output, in [0,1]
  f4 u = { expf(p[0]), expf(p[1]), expf(p[2]), expf(p[3]) };  // in [1,e] -> fp16-friendly
  h4 uh = __builtin_convertvector(u, h4);
  f4 ur = __builtin_convertvector(uh, f4);   // rounded value: keep colsum consistent with stored u
  if (valid) ((h4*)uout)[(size_t)node*8 + sl] = uh;
  __syncthreads();
  sAv[nl][c]   = valid ? ur[0] : 0.0f;
  sAv[nl][c+1] = valid ? ur[1] : 0.0f;
  sAv[nl][c+2] = valid ? ur[2] : 0.0f;
  sAv[nl][c+3] = valid ? ur[3] : 0.0f;
  __syncthreads();
  if (tid < 32){
    float s = sAv[0][tid];
    #pragma unroll
    for (int nd=1; nd<NPB; nd++) s += sAv[nd][tid];
    atomicAdd(&cs_next[tid], s);
  }
}

// ---------------- output layer: z = (u * rc) @ W_out + b, then softmax over nodes ----------------

__global__ __launch_bounds__(256) void k_out1(const _Float16* __restrict__ u, const float* __restrict__ W,
    const float* __restrict__ bptr, const float* __restrict__ cs_last,
    float* __restrict__ z, unsigned* __restrict__ zmaxkey, int n){
  __shared__ float ws[32];
  __shared__ float red[256];
  int tid = threadIdx.x;
  if (tid < 32) ws[tid] = W[tid] * (1.0f / cs_last[tid]);
  __syncthreads();
  int node = blockIdx.x*256 + tid;
  float zz = -3.0e38f;
  if (node < n){
    float acc = bptr[0];
    const h4* ur = (const h4*)u + (size_t)node*8;
    #pragma unroll
    for (int q=0;q<8;q++){
      f4 a = __builtin_convertvector(ur[q], f4);
      f4 w = ((const f4*)ws)[q];
      acc += a[0]*w[0] + a[1]*w[1] + a[2]*w[2] + a[3]*w[3];
    }
    z[node]=acc; zz=acc;
  }
  red[tid]=zz; __syncthreads();
  for (int s=128;s>0;s>>=1){
    if (tid<s) red[tid]=fmaxf(red[tid],red[tid+s]);
    __syncthreads();
  }
  if (tid==0) atomicMax(zmaxkey, f2key(red[0]));
}

__global__ __launch_bounds__(256) void k_out2(const float* __restrict__ z, const unsigned* __restrict__ zmaxkey,
                                              float* __restrict__ zsum, int n){
  __shared__ float red[256];
  int tid = threadIdx.x;
  int node = blockIdx.x*256 + tid;
  float zmax = key2f(*zmaxkey);
  float v = (node<n) ? expf(z[node]-zmax) : 0.0f;
  red[tid]=v; __syncthreads();
  for (int s=128;s>0;s>>=1){
    if (tid<s) red[tid]+=red[tid+s];
    __syncthreads();
  }
  if (tid==0) atomicAdd(zsum, red[0]);
}

__global__ __launch_bounds__(256) void k_out3(const float* __restrict__ z, const unsigned* __restrict__ zmaxkey,
                                              const float* __restrict__ zsum, float* __restrict__ out, int n){
  int node = blockIdx.x*256 + threadIdx.x;
  if (node < n){
    float zmax = key2f(*zmaxkey);
    out[node] = expf(z[node]-zmax) / (*zsum);
  }
}

// ---------------- host launcher ----------------

extern "C" void kernel_launch(void* const* d_in, const int* in_sizes, int n_in,
                              void* d_out, int out_size, void* d_ws, size_t ws_size,
                              hipStream_t stream) {
  const float* x      = (const float*)d_in[0];
  const int*   ei     = (const int*)d_in[1];   // int64 in reference -> int32 on device per harness
  const float* A_in   = (const float*)d_in[2];
  const float* B_in   = (const float*)d_in[3];
  const float* A_conv = (const float*)d_in[4];
  const float* B_conv = (const float*)d_in[5];
  const float* W_out  = (const float*)d_in[6];
  const float* b_out  = (const float*)d_in[7];
  const int N = in_sizes[0] / 4;
  const int E = in_sizes[1] / 2;
  const int NROUNDS = 16;

  char* w = (char*)d_ws;
  size_t o = 0;
  auto alloc = [&](size_t bytes)->char* {
    char* p = w + o;
    o = (o + bytes + 15) & ~(size_t)15;
    return p;
  };
  // ---- zero-init control region (one memset) ----
  int*      deg8    = (int*)     alloc((size_t)NSEG*N*4);
  float*    colsum  = (float*)   alloc((size_t)NROUNDS*32*4);
  unsigned* zmaxkey = (unsigned*)alloc(4);
  float*    zsum    = (float*)   alloc(4);
  size_t ctrl_bytes = o;
  // ---- rest ----
  int*   offs    = (int*)  alloc((size_t)(N+1)*4);
  int*   cursor8 = (int*)  alloc((size_t)NSEG*N*4);
  float* invdeg  = (float*)alloc((size_t)N*4);
  int    nb      = (N + 1023) / 1024;
  int*   bsum    = (int*)  alloc((size_t)nb*4);
  int*   bpre    = (int*)  alloc((size_t)nb*4);
  int*   csr     = (int*)  alloc((size_t)E*4);
  _Float16* uA   = (_Float16*)alloc((size_t)N*32*2);
  _Float16* uB   = (_Float16*)alloc((size_t)N*32*2);
  float* zbuf    = (float*)uB;  // uB free when k_out1 runs (final u lands in uA)
  (void)ws_size; (void)n_in; (void)out_size;

  hipMemsetAsync(d_ws, 0, ctrl_bytes, stream);

  int gridE = (E + 255) / 256;
  int gridN = (N + 255) / 256;
  int gridC = (N + NPB - 1) / NPB;

  // CSR build
  k_deg  <<<gridE, 256, 0, stream>>>(ei, deg8, E, N);
  k_scan1<<<nb, 1024, 0, stream>>>(deg8, offs, bsum, N);
  k_scan2<<<1, 64, 0, stream>>>(bsum, bpre, nb);
  k_scan3<<<gridN, 256, 0, stream>>>(offs, bpre, deg8, cursor8, invdeg, N, E);
  k_fill <<<gridE, 256, 0, stream>>>(ei, cursor8, csr, E, N);

  // proj_in -> u0 (rc0 = 1)
  k_in<<<gridN, 256, 0, stream>>>(x, uA, offs, csr, invdeg, A_in, B_in, N);

  // 16 conv rounds, one kernel each; rc folded into weights from previous round's colsum
  for (int r = 0; r < NROUNDS; r++){
    const float* Wa = A_conv + (size_t)r*32*32;
    const float* Wb = B_conv + (size_t)r*32*32;
    const float* cs_prev = (r == 0) ? nullptr : (colsum + (size_t)(r-1)*32);
    float*       cs_next = colsum + (size_t)r*32;
    const _Float16* ui = (r & 1) ? uB : uA;
    _Float16*       uo = (r & 1) ? uA : uB;
    k_conv<<<gridC, 256, 0, stream>>>(ui, uo, offs, csr, invdeg, Wa, Wb, cs_prev, cs_next, N);
  }

  // output layer (final u in uA after 16 rounds; rc16 folded into W_out)
  k_out1<<<gridN, 256, 0, stream>>>(uA, W_out, b_out, colsum + (size_t)(NROUNDS-1)*32, zbuf, zmaxkey, N);
  k_out2<<<gridN, 256, 0, stream>>>(zbuf, zmaxkey, zsum, N);
  k_out3<<<gridN, 256, 0, stream>>>(zbuf, zmaxkey, zsum, (float*)d_out, N);
}

// Round 4
// 1644.746 us; speedup vs baseline: 1.6828x; 1.2760x over previous
//
#include <hip/hip_runtime.h>

#define NPB 32   // nodes per block in k_conv (256 threads, 8 lanes/node)
#define NSEG 8
#define SEGSH 19 // k_deg: segment = edge >> 19
#define NGRP 16  // k_fill: dst-range groups; group = blockIdx%16 -> fixed XCD (b%8)
#define CHUNK 2048

typedef float    f4 __attribute__((ext_vector_type(4)));
typedef _Float16 h4 __attribute__((ext_vector_type(4)));

__device__ __forceinline__ unsigned f2key(float x){
  unsigned b = __float_as_uint(x);
  return (b & 0x80000000u) ? ~b : (b | 0x80000000u);
}
__device__ __forceinline__ float key2f(unsigned k){
  return (k & 0x80000000u) ? __uint_as_float(k ^ 0x80000000u) : __uint_as_float(~k);
}

// ---------------- CSR build ----------------

__global__ void k_deg(const int* __restrict__ ei, int* __restrict__ deg8, int E, int n){
  int e = blockIdx.x*blockDim.x + threadIdx.x;
  if (e < E){
    int d = ei[E + e];
    int seg = e >> SEGSH; if (seg > NSEG-1) seg = NSEG-1;
    if ((unsigned)d < (unsigned)n) atomicAdd(&deg8[seg*n + d], 1);
  }
}

__global__ __launch_bounds__(1024) void k_scan1(const int* __restrict__ deg8, int* __restrict__ offs,
                                                int* __restrict__ bsum, int n){
  __shared__ int tmp[1024];
  int tid = threadIdx.x;
  int gid = blockIdx.x*1024 + tid;
  int v = 0;
  if (gid < n){
    #pragma unroll
    for (int s=0;s<NSEG;s++) v += deg8[s*n + gid];
  }
  tmp[tid] = v;
  __syncthreads();
  for (int o=1;o<1024;o<<=1){
    int t = (tid>=o) ? tmp[tid-o] : 0;
    __syncthreads();
    if (tid>=o) tmp[tid] += t;
    __syncthreads();
  }
  int inc = tmp[tid];
  if (gid < n) offs[gid] = inc - v;   // exclusive within chunk
  if (tid == 1023) bsum[blockIdx.x] = inc;
}

__global__ void k_scan2(const int* __restrict__ bsum, int* __restrict__ bpre, int nb){
  if (threadIdx.x==0 && blockIdx.x==0){
    int acc=0;
    for (int i=0;i<nb;i++){ bpre[i]=acc; acc+=bsum[i]; }
  }
}

__global__ void k_scan3(int* __restrict__ offs, const int* __restrict__ bpre,
                        const int* __restrict__ deg8, int* __restrict__ cursor,
                        float* __restrict__ invdeg, int n, int E){
  int gid = blockIdx.x*blockDim.x + threadIdx.x;
  if (gid < n){
    int base = offs[gid] + bpre[gid>>10];
    offs[gid] = base;
    cursor[gid] = base;
    int dtot = 0;
    #pragma unroll
    for (int s=0;s<NSEG;s++) dtot += deg8[s*n + gid];
    invdeg[gid] = 1.0f / (float)(dtot>0?dtot:1);
  }
  if (gid==0) offs[n] = E;
}

// Each dst-range group g is processed only by blocks with blockIdx%NGRP==g, which all
// share one XCD (blockIdx%8) -> each csr region is dirtied by ONE L2 -> one writeback.
__global__ __launch_bounds__(256) void k_fill(const int* __restrict__ ei, int* __restrict__ cursor,
                                              int* __restrict__ csr, int E, int n){
  int g = blockIdx.x & (NGRP-1);
  int j = blockIdx.x >> 4;
  int span = (n + NGRP - 1) / NGRP;
  int lo = g * span;
  int base = j * CHUNK;
  if (base >= E) return;
  int end = base + CHUNK; if (end > E) end = E;
  for (int e = base + threadIdx.x; e < end; e += 256){
    int d = ei[E + e];
    if ((unsigned)(d - lo) < (unsigned)span && (unsigned)d < (unsigned)n){
      int s = ei[e];
      if ((unsigned)s < (unsigned)n){
        int pos = atomicAdd(&cursor[d], 1);
        if ((unsigned)pos < (unsigned)E) csr[pos] = s;
      }
    }
  }
}

// ---------------- proj_in: gather x[4] + (avg@A + x@B) + row softmax -> u0 = p (fp16) ----------------

__global__ __launch_bounds__(256) void k_in(const float* __restrict__ x, _Float16* __restrict__ uout,
    const int* __restrict__ offs, const int* __restrict__ csr, const float* __restrict__ invdeg,
    const float* __restrict__ A, const float* __restrict__ B, int n){
  __shared__ float sA[128], sB[128];
  int tid = threadIdx.x;
  if (tid < 128){ sA[tid]=A[tid]; sB[tid]=B[tid]; }
  __syncthreads();
  int node = blockIdx.x*256 + tid;
  if (node >= n) return;
  float4 s = {0,0,0,0};
  int b0=offs[node], e0=offs[node+1];
  for (int k=b0;k<e0;k++){
    int sid = csr[k];
    float4 v = ((const float4*)x)[sid];
    s.x+=v.x; s.y+=v.y; s.z+=v.z; s.w+=v.w;
  }
  float idg = invdeg[node];
  s.x*=idg; s.y*=idg; s.z*=idg; s.w*=idg;
  float4 xr = ((const float4*)x)[node];
  float z[32];
  #pragma unroll
  for (int j=0;j<32;j++){
    z[j] = s.x*sA[j] + s.y*sA[32+j] + s.z*sA[64+j] + s.w*sA[96+j]
         + xr.x*sB[j] + xr.y*sB[32+j] + xr.z*sB[64+j] + xr.w*sB[96+j];
  }
  float m = z[0];
  #pragma unroll
  for (int j=1;j<32;j++) m = fmaxf(m,z[j]);
  float sum=0.0f;
  #pragma unroll
  for (int j=0;j<32;j++){ z[j]=expf(z[j]-m); sum+=z[j]; }
  float r = 1.0f/sum;
  h4* op = (h4*)uout + (size_t)node*8;
  #pragma unroll
  for (int q=0;q<8;q++){
    f4 t = { z[4*q]*r, z[4*q+1]*r, z[4*q+2]*r, z[4*q+3]*r };
    op[q] = __builtin_convertvector(t, h4);
  }
}

// ---------------- conv round (fused): gather u (fp16) + dual matmul (rc folded) + row softmax
//                  -> u' = exp(p) (fp16) + column sums ----------------

__global__ __launch_bounds__(256, 8) void k_conv(
    const _Float16* __restrict__ uin, _Float16* __restrict__ uout,
    const int* __restrict__ offs, const int* __restrict__ csr,
    const float* __restrict__ invdeg,
    const float* __restrict__ Wa, const float* __restrict__ Wb,
    const float* __restrict__ cs_prev, float* __restrict__ cs_next, int n){
  __shared__ float sWa[1024], sWb[1024];
  __shared__ float sAv[NPB][33], sOwn[NPB][33];
  int tid = threadIdx.x;
  float rcf = 1.0f;
  if (cs_prev) rcf = 1.0f / cs_prev[tid>>3];   // row f = tid/8 of the [32][32] weight
  ((f4*)sWa)[tid] = ((const f4*)Wa)[tid] * rcf;
  ((f4*)sWb)[tid] = ((const f4*)Wb)[tid] * rcf;
  int nl = tid>>3, sl = tid&7;
  int node = blockIdx.x*NPB + nl;
  bool valid = node < n;
  f4 acc = {0,0,0,0}, own = {0,0,0,0};
  if (valid){
    f4 a0 = {0,0,0,0}, a1 = {0,0,0,0};
    int b0=offs[node], e0=offs[node+1];
    const h4* ub = (const h4*)uin;
    int k=b0;
    for (; k+4<=e0; k+=4){
      int s0=csr[k], s1=csr[k+1], s2=csr[k+2], s3=csr[k+3];
      h4 v0 = ub[(size_t)s0*8 + sl];
      h4 v1 = ub[(size_t)s1*8 + sl];
      h4 v2 = ub[(size_t)s2*8 + sl];
      h4 v3 = ub[(size_t)s3*8 + sl];
      a0 += __builtin_convertvector(v0, f4) + __builtin_convertvector(v1, f4);
      a1 += __builtin_convertvector(v2, f4) + __builtin_convertvector(v3, f4);
    }
    for (; k<e0; k++) a0 += __builtin_convertvector(ub[(size_t)csr[k]*8 + sl], f4);
    acc = (a0 + a1) * invdeg[node];
    own = __builtin_convertvector(ub[(size_t)node*8 + sl], f4);
  }
  int c = sl*4;
  sAv[nl][c]=acc[0]; sAv[nl][c+1]=acc[1]; sAv[nl][c+2]=acc[2]; sAv[nl][c+3]=acc[3];
  sOwn[nl][c]=own[0]; sOwn[nl][c+1]=own[1]; sOwn[nl][c+2]=own[2]; sOwn[nl][c+3]=own[3];
  __syncthreads();
  f4 z = {0,0,0,0};
  #pragma unroll
  for (int f=0; f<32; f++){
    float a = sAv[nl][f], o = sOwn[nl][f];
    f4 wa = ((const f4*)(sWa + f*32))[sl];
    f4 wb = ((const f4*)(sWb + f*32))[sl];
    z += a*wa + o*wb;
  }
  float m = fmaxf(fmaxf(z[0],z[1]), fmaxf(z[2],z[3]));
  m = fmaxf(m, __shfl_xor(m,1));
  m = fmaxf(m, __shfl_xor(m,2));
  m = fmaxf(m, __shfl_xor(m,4));
  f4 ev = { expf(z[0]-m), expf(z[1]-m), expf(z[2]-m), expf(z[3]-m) };
  float ss = ev[0]+ev[1]+ev[2]+ev[3];
  ss += __shfl_xor(ss,1);
  ss += __shfl_xor(ss,2);
  ss += __shfl_xor(ss,4);
  float r = 1.0f/ss;
  f4 p = ev*r;                       // row-softmax output, in [0,1]
  f4 u = { expf(p[0]), expf(p[1]), expf(p[2]), expf(p[3]) };
  h4 uh = __builtin_convertvector(u, h4);
  f4 ur = __builtin_convertvector(uh, f4);   // rounded value: colsum consistent with stored u
  if (valid) ((h4*)uout)[(size_t)node*8 + sl] = uh;
  __syncthreads();
  sAv[nl][c]   = valid ? ur[0] : 0.0f;
  sAv[nl][c+1] = valid ? ur[1] : 0.0f;
  sAv[nl][c+2] = valid ? ur[2] : 0.0f;
  sAv[nl][c+3] = valid ? ur[3] : 0.0f;
  __syncthreads();
  if (tid < 32){
    float s = sAv[0][tid];
    #pragma unroll
    for (int nd=1; nd<NPB; nd++) s += sAv[nd][tid];
    atomicAdd(&cs_next[tid], s);
  }
}

// ---------------- output layer ----------------

__global__ __launch_bounds__(256) void k_out1(const _Float16* __restrict__ u, const float* __restrict__ W,
    const float* __restrict__ bptr, const float* __restrict__ cs_last,
    float* __restrict__ z, unsigned* __restrict__ zmaxkey, int n){
  __shared__ float ws[32];
  __shared__ float red[256];
  int tid = threadIdx.x;
  if (tid < 32) ws[tid] = W[tid] * (1.0f / cs_last[tid]);
  __syncthreads();
  int node = blockIdx.x*256 + tid;
  float zz = -3.0e38f;
  if (node < n){
    float acc = bptr[0];
    const h4* ur = (const h4*)u + (size_t)node*8;
    #pragma unroll
    for (int q=0;q<8;q++){
      f4 a = __builtin_convertvector(ur[q], f4);
      f4 w = ((const f4*)ws)[q];
      acc += a[0]*w[0] + a[1]*w[1] + a[2]*w[2] + a[3]*w[3];
    }
    z[node]=acc; zz=acc;
  }
  red[tid]=zz; __syncthreads();
  for (int s=128;s>0;s>>=1){
    if (tid<s) red[tid]=fmaxf(red[tid],red[tid+s]);
    __syncthreads();
  }
  if (tid==0) atomicMax(zmaxkey, f2key(red[0]));
}

__global__ __launch_bounds__(256) void k_out2(const float* __restrict__ z, const unsigned* __restrict__ zmaxkey,
                                              float* __restrict__ zsum, int n){
  __shared__ float red[256];
  int tid = threadIdx.x;
  int node = blockIdx.x*256 + tid;
  float zmax = key2f(*zmaxkey);
  float v = (node<n) ? expf(z[node]-zmax) : 0.0f;
  red[tid]=v; __syncthreads();
  for (int s=128;s>0;s>>=1){
    if (tid<s) red[tid]+=red[tid+s];
    __syncthreads();
  }
  if (tid==0) atomicAdd(zsum, red[0]);
}

__global__ __launch_bounds__(256) void k_out3(const float* __restrict__ z, const unsigned* __restrict__ zmaxkey,
                                              const float* __restrict__ zsum, float* __restrict__ out, int n){
  int node = blockIdx.x*256 + threadIdx.x;
  if (node < n){
    float zmax = key2f(*zmaxkey);
    out[node] = expf(z[node]-zmax) / (*zsum);
  }
}

// ---------------- host launcher ----------------

extern "C" void kernel_launch(void* const* d_in, const int* in_sizes, int n_in,
                              void* d_out, int out_size, void* d_ws, size_t ws_size,
                              hipStream_t stream) {
  const float* x      = (const float*)d_in[0];
  const int*   ei     = (const int*)d_in[1];   // int64 in reference -> int32 on device per harness
  const float* A_in   = (const float*)d_in[2];
  const float* B_in   = (const float*)d_in[3];
  const float* A_conv = (const float*)d_in[4];
  const float* B_conv = (const float*)d_in[5];
  const float* W_out  = (const float*)d_in[6];
  const float* b_out  = (const float*)d_in[7];
  const int N = in_sizes[0] / 4;
  const int E = in_sizes[1] / 2;
  const int NROUNDS = 16;

  char* w = (char*)d_ws;
  size_t o = 0;
  auto alloc = [&](size_t bytes)->char* {
    char* p = w + o;
    o = (o + bytes + 15) & ~(size_t)15;
    return p;
  };
  // ---- zero-init control region (one memset) ----
  int*      deg8    = (int*)     alloc((size_t)NSEG*N*4);
  float*    colsum  = (float*)   alloc((size_t)NROUNDS*32*4);
  unsigned* zmaxkey = (unsigned*)alloc(4);
  float*    zsum    = (float*)   alloc(4);
  size_t ctrl_bytes = o;
  // ---- rest ----
  int*   offs    = (int*)  alloc((size_t)(N+1)*4);
  int*   cursor  = (int*)  alloc((size_t)N*4);
  float* invdeg  = (float*)alloc((size_t)N*4);
  int    nb      = (N + 1023) / 1024;
  int*   bsum    = (int*)  alloc((size_t)nb*4);
  int*   bpre    = (int*)  alloc((size_t)nb*4);
  int*   csr     = (int*)  alloc((size_t)E*4);
  _Float16* uA   = (_Float16*)alloc((size_t)N*32*2);
  _Float16* uB   = (_Float16*)alloc((size_t)N*32*2);
  float* zbuf    = (float*)uB;  // uB free when k_out1 runs (final u lands in uA)
  (void)ws_size; (void)n_in; (void)out_size;

  hipMemsetAsync(d_ws, 0, ctrl_bytes, stream);

  int gridE = (E + 255) / 256;
  int gridN = (N + 255) / 256;
  int gridC = (N + NPB - 1) / NPB;
  int bpg   = (E + CHUNK - 1) / CHUNK;

  // CSR build
  k_deg  <<<gridE, 256, 0, stream>>>(ei, deg8, E, N);
  k_scan1<<<nb, 1024, 0, stream>>>(deg8, offs, bsum, N);
  k_scan2<<<1, 64, 0, stream>>>(bsum, bpre, nb);
  k_scan3<<<gridN, 256, 0, stream>>>(offs, bpre, deg8, cursor, invdeg, N, E);
  k_fill <<<NGRP*bpg, 256, 0, stream>>>(ei, cursor, csr, E, N);

  // proj_in -> u0
  k_in<<<gridN, 256, 0, stream>>>(x, uA, offs, csr, invdeg, A_in, B_in, N);

  // 16 conv rounds
  for (int r = 0; r < NROUNDS; r++){
    const float* Wa = A_conv + (size_t)r*32*32;
    const float* Wb = B_conv + (size_t)r*32*32;
    const float* cs_prev = (r == 0) ? nullptr : (colsum + (size_t)(r-1)*32);
    float*       cs_next = colsum + (size_t)r*32;
    const _Float16* ui = (r & 1) ? uB : uA;
    _Float16*       uo = (r & 1) ? uA : uB;
    k_conv<<<gridC, 256, 0, stream>>>(ui, uo, offs, csr, invdeg, Wa, Wb, cs_prev, cs_next, N);
  }

  // output layer (rc16 folded into W_out)
  k_out1<<<gridN, 256, 0, stream>>>(uA, W_out, b_out, colsum + (size_t)(NROUNDS-1)*32, zbuf, zmaxkey, N);
  k_out2<<<gridN, 256, 0, stream>>>(zbuf, zmaxkey, zsum, N);
  k_out3<<<gridN, 256, 0, stream>>>(zbuf, zmaxkey, zsum, (float*)d_out, N);
}

// Round 5
// 1478.770 us; speedup vs baseline: 1.8717x; 1.1122x over previous
//
#include <hip/hip_runtime.h>

#define NSEG 8
#define SEGSH 19 // k_deg: segment = edge >> 19
#define NGRP 8   // k_fill: dst-range groups; group = blockIdx%8 -> fixed XCD
#define CHUNK 2048
#define CSTR 64  // colsum element stride (256B) -> spread across L2 slices

typedef float    f4 __attribute__((ext_vector_type(4)));
typedef float    f8 __attribute__((ext_vector_type(8)));
typedef _Float16 h4 __attribute__((ext_vector_type(4)));
typedef _Float16 h8 __attribute__((ext_vector_type(8)));

__device__ __forceinline__ unsigned f2key(float x){
  unsigned b = __float_as_uint(x);
  return (b & 0x80000000u) ? ~b : (b | 0x80000000u);
}
__device__ __forceinline__ float key2f(unsigned k){
  return (k & 0x80000000u) ? __uint_as_float(k ^ 0x80000000u) : __uint_as_float(~k);
}

// ---------------- CSR build ----------------

__global__ void k_deg(const int* __restrict__ ei, int* __restrict__ deg8, int E, int n){
  int e = blockIdx.x*blockDim.x + threadIdx.x;
  if (e < E){
    int d = ei[E + e];
    int seg = e >> SEGSH; if (seg > NSEG-1) seg = NSEG-1;
    if ((unsigned)d < (unsigned)n) atomicAdd(&deg8[seg*n + d], 1);
  }
}

__global__ __launch_bounds__(1024) void k_scan1(const int* __restrict__ deg8, int* __restrict__ offs,
                                                int* __restrict__ bsum, int n){
  __shared__ int tmp[1024];
  int tid = threadIdx.x;
  int gid = blockIdx.x*1024 + tid;
  int v = 0;
  if (gid < n){
    #pragma unroll
    for (int s=0;s<NSEG;s++) v += deg8[s*n + gid];
  }
  tmp[tid] = v;
  __syncthreads();
  for (int o=1;o<1024;o<<=1){
    int t = (tid>=o) ? tmp[tid-o] : 0;
    __syncthreads();
    if (tid>=o) tmp[tid] += t;
    __syncthreads();
  }
  int inc = tmp[tid];
  if (gid < n) offs[gid] = inc - v;   // exclusive within chunk
  if (tid == 1023) bsum[blockIdx.x] = inc;
}

__global__ void k_scan2(const int* __restrict__ bsum, int* __restrict__ bpre, int nb){
  if (threadIdx.x==0 && blockIdx.x==0){
    int acc=0;
    for (int i=0;i<nb;i++){ bpre[i]=acc; acc+=bsum[i]; }
  }
}

__global__ void k_scan3(int* __restrict__ offs, const int* __restrict__ bpre,
                        const int* __restrict__ deg8, int* __restrict__ cursor,
                        float* __restrict__ invdeg, int n, int E){
  int gid = blockIdx.x*blockDim.x + threadIdx.x;
  if (gid < n){
    int base = offs[gid] + bpre[gid>>10];
    offs[gid] = base;
    cursor[gid] = base;
    int dtot = 0;
    #pragma unroll
    for (int s=0;s<NSEG;s++) dtot += deg8[s*n + gid];
    invdeg[gid] = 1.0f / (float)(dtot>0?dtot:1);
  }
  if (gid==0) offs[n] = E;
}

__global__ __launch_bounds__(256) void k_fill(const int* __restrict__ ei, int* __restrict__ cursor,
                                              int* __restrict__ csr, int E, int n){
  int g = blockIdx.x & (NGRP-1);
  int j = blockIdx.x >> 3;
  int span = (n + NGRP - 1) / NGRP;
  int lo = g * span;
  int base = j * CHUNK;
  if (base >= E) return;
  int end = base + CHUNK; if (end > E) end = E;
  for (int e = base + threadIdx.x; e < end; e += 256){
    int d = ei[E + e];
    if ((unsigned)(d - lo) < (unsigned)span && (unsigned)d < (unsigned)n){
      int s = ei[e];
      if ((unsigned)s < (unsigned)n){
        int pos = atomicAdd(&cursor[d], 1);
        if ((unsigned)pos < (unsigned)E) csr[pos] = s;
      }
    }
  }
}

// ---------------- proj_in: gather x[4] + (avg@A + x@B) + row softmax -> u0 = p (fp16) ----------------

__global__ __launch_bounds__(256) void k_in(const float* __restrict__ x, _Float16* __restrict__ uout,
    const int* __restrict__ offs, const int* __restrict__ csr, const float* __restrict__ invdeg,
    const float* __restrict__ A, const float* __restrict__ B, int n){
  __shared__ float sA[128], sB[128];
  int tid = threadIdx.x;
  if (tid < 128){ sA[tid]=A[tid]; sB[tid]=B[tid]; }
  __syncthreads();
  int node = blockIdx.x*256 + tid;
  if (node >= n) return;
  float4 s = {0,0,0,0};
  int b0=offs[node], e0=offs[node+1];
  for (int k=b0;k<e0;k++){
    int sid = csr[k];
    float4 v = ((const float4*)x)[sid];
    s.x+=v.x; s.y+=v.y; s.z+=v.z; s.w+=v.w;
  }
  float idg = invdeg[node];
  s.x*=idg; s.y*=idg; s.z*=idg; s.w*=idg;
  float4 xr = ((const float4*)x)[node];
  float z[32];
  #pragma unroll
  for (int j=0;j<32;j++){
    z[j] = s.x*sA[j] + s.y*sA[32+j] + s.z*sA[64+j] + s.w*sA[96+j]
         + xr.x*sB[j] + xr.y*sB[32+j] + xr.z*sB[64+j] + xr.w*sB[96+j];
  }
  float m = z[0];
  #pragma unroll
  for (int j=1;j<32;j++) m = fmaxf(m,z[j]);
  float sum=0.0f;
  #pragma unroll
  for (int j=0;j<32;j++){ z[j]=expf(z[j]-m); sum+=z[j]; }
  float r = 1.0f/sum;
  h4* op = (h4*)uout + (size_t)node*8;
  #pragma unroll
  for (int q=0;q<8;q++){
    f4 t = { z[4*q]*r, z[4*q+1]*r, z[4*q+2]*r, z[4*q+3]*r };
    op[q] = __builtin_convertvector(t, h4);
  }
}

// ---------------- conv round (MFMA): wave = 16 nodes; gather u (fp16, 16B/lane k-chunk),
//  z = [avg|own] @ [Wa;Wb] via 2x chained mfma_f32_16x16x32_f16 per out-half,
//  row softmax via 16-lane shfl, u' = exp(p), colsum via shfl+LDS+strided atomics.
//  Weights folded with rho = 2^17/colsum (fp16-safe), Rscale = 2^-17 applied to z in f32. ----------------

__global__ __launch_bounds__(256) void k_conv(
    const _Float16* __restrict__ uin, _Float16* __restrict__ uout,
    const int* __restrict__ offs, const int* __restrict__ csr,
    const float* __restrict__ invdeg,
    const float* __restrict__ Wa, const float* __restrict__ Wb,
    const float* __restrict__ cs_prev, float Rscale, float* __restrict__ cs_next, int n){
  __shared__ float sWa[1024], sWb[1024];
  __shared__ float sCol[32];
  int tid = threadIdx.x;
  float rcf = 1.0f;
  if (cs_prev) rcf = 131072.0f / cs_prev[(tid>>3)*CSTR];  // rho = 2^17/cs, in [0.48, 1.31]
  ((f4*)sWa)[tid] = ((const f4*)Wa)[tid] * rcf;
  ((f4*)sWb)[tid] = ((const f4*)Wb)[tid] * rcf;
  if (tid < 32) sCol[tid] = 0.0f;
  __syncthreads();

  int lane = tid & 63;
  int wv   = tid >> 6;
  int q    = lane >> 4;         // k-chunk (A) / row-quad (C)
  int c    = lane & 15;         // gather node (A's m) / output column (B's n, C's col)
  int tile = blockIdx.x*64 + wv*16;
  int node = tile + c;
  bool gv = node < n;

  // B-fragments in registers: B[k][n], k = q*8+j, n = c (lo) / c+16 (hi)
  h8 waLo, waHi, wbLo, wbHi;
  #pragma unroll
  for (int j=0;j<8;j++){
    int k = q*8 + j;
    waLo[j] = (_Float16)sWa[k*32 + c];
    waHi[j] = (_Float16)sWa[k*32 + c + 16];
    wbLo[j] = (_Float16)sWb[k*32 + c];
    wbHi[j] = (_Float16)sWb[k*32 + c + 16];
  }

  // gather: mean of neighbor u rows, this lane covers halves [q*8, q*8+8) of node `tile+c`
  f8 a0 = {0,0,0,0,0,0,0,0}, a1 = {0,0,0,0,0,0,0,0};
  f8 a2 = {0,0,0,0,0,0,0,0}, a3 = {0,0,0,0,0,0,0,0};
  int b0 = gv ? offs[node]   : 0;
  int e0 = gv ? offs[node+1] : 0;
  const h8* ub = (const h8*)uin;
  int k = b0;
  for (; k+4<=e0; k+=4){
    int s0=csr[k], s1=csr[k+1], s2=csr[k+2], s3=csr[k+3];
    h8 v0 = ub[(size_t)s0*4 + q];
    h8 v1 = ub[(size_t)s1*4 + q];
    h8 v2 = ub[(size_t)s2*4 + q];
    h8 v3 = ub[(size_t)s3*4 + q];
    a0 += __builtin_convertvector(v0, f8);
    a1 += __builtin_convertvector(v1, f8);
    a2 += __builtin_convertvector(v2, f8);
    a3 += __builtin_convertvector(v3, f8);
  }
  for (; k<e0; k++) a0 += __builtin_convertvector(ub[(size_t)csr[k]*4 + q], f8);
  a0 = (a0 + a1) + (a2 + a3);
  float idg = gv ? invdeg[node] : 0.0f;
  a0 *= idg;
  h8 afrag = __builtin_convertvector(a0, h8);
  h8 ofrag = {0,0,0,0,0,0,0,0};
  if (gv) ofrag = ub[(size_t)node*4 + q];

  f4 z1 = {0,0,0,0}, z2 = {0,0,0,0};
  z1 = __builtin_amdgcn_mfma_f32_16x16x32_f16(ofrag, wbLo, z1, 0, 0, 0);
  z1 = __builtin_amdgcn_mfma_f32_16x16x32_f16(afrag, waLo, z1, 0, 0, 0);
  z2 = __builtin_amdgcn_mfma_f32_16x16x32_f16(ofrag, wbHi, z2, 0, 0, 0);
  z2 = __builtin_amdgcn_mfma_f32_16x16x32_f16(afrag, waHi, z2, 0, 0, 0);
  z1 *= Rscale; z2 *= Rscale;

  // C layout: row (node-in-tile) = q*4 + r, col = c (z1) / c+16 (z2)
  f4 mx, sm;
  #pragma unroll
  for (int r=0;r<4;r++) mx[r] = fmaxf(z1[r], z2[r]);
  #pragma unroll
  for (int s=1;s<16;s<<=1){
    #pragma unroll
    for (int r=0;r<4;r++) mx[r] = fmaxf(mx[r], __shfl_xor(mx[r], s));
  }
  #pragma unroll
  for (int r=0;r<4;r++){
    z1[r] = expf(z1[r]-mx[r]);
    z2[r] = expf(z2[r]-mx[r]);
    sm[r] = z1[r] + z2[r];
  }
  #pragma unroll
  for (int s=1;s<16;s<<=1){
    #pragma unroll
    for (int r=0;r<4;r++) sm[r] += __shfl_xor(sm[r], s);
  }
  float cs1 = 0.0f, cs2 = 0.0f;
  #pragma unroll
  for (int r=0;r<4;r++){
    float rs = 1.0f/sm[r];
    float u1 = expf(z1[r]*rs);     // u = exp(p), p in [0,1]
    float u2 = expf(z2[r]*rs);
    _Float16 uh1 = (_Float16)u1, uh2 = (_Float16)u2;
    int nd = tile + q*4 + r;
    if (nd < n){
      uout[(size_t)nd*32 + c]      = uh1;
      uout[(size_t)nd*32 + c + 16] = uh2;
      cs1 += (float)uh1;           // colsum consistent with stored (rounded) u
      cs2 += (float)uh2;
    }
  }
  cs1 += __shfl_xor(cs1, 16); cs1 += __shfl_xor(cs1, 32);
  cs2 += __shfl_xor(cs2, 16); cs2 += __shfl_xor(cs2, 32);
  if (lane < 16){
    atomicAdd(&sCol[c],      cs1);
    atomicAdd(&sCol[c + 16], cs2);
  }
  __syncthreads();
  if (tid < 32) atomicAdd(&cs_next[tid*CSTR], sCol[tid]);
}

// ---------------- output layer ----------------

__global__ __launch_bounds__(256) void k_out1(const _Float16* __restrict__ u, const float* __restrict__ W,
    const float* __restrict__ bptr, const float* __restrict__ cs_last,
    float* __restrict__ z, unsigned* __restrict__ zmaxkey, int n){
  __shared__ float ws[32];
  __shared__ float red[256];
  int tid = threadIdx.x;
  if (tid < 32) ws[tid] = W[tid] * (1.0f / cs_last[tid*CSTR]);
  __syncthreads();
  int node = blockIdx.x*256 + tid;
  float zz = -3.0e38f;
  if (node < n){
    float acc = bptr[0];
    const h4* ur = (const h4*)u + (size_t)node*8;
    #pragma unroll
    for (int q=0;q<8;q++){
      f4 a = __builtin_convertvector(ur[q], f4);
      f4 w = ((const f4*)ws)[q];
      acc += a[0]*w[0] + a[1]*w[1] + a[2]*w[2] + a[3]*w[3];
    }
    z[node]=acc; zz=acc;
  }
  red[tid]=zz; __syncthreads();
  for (int s=128;s>0;s>>=1){
    if (tid<s) red[tid]=fmaxf(red[tid],red[tid+s]);
    __syncthreads();
  }
  if (tid==0) atomicMax(zmaxkey, f2key(red[0]));
}

__global__ __launch_bounds__(256) void k_out2(const float* __restrict__ z, const unsigned* __restrict__ zmaxkey,
                                              float* __restrict__ zsum, int n){
  __shared__ float red[256];
  int tid = threadIdx.x;
  int node = blockIdx.x*256 + tid;
  float zmax = key2f(*zmaxkey);
  float v = (node<n) ? expf(z[node]-zmax) : 0.0f;
  red[tid]=v; __syncthreads();
  for (int s=128;s>0;s>>=1){
    if (tid<s) red[tid]+=red[tid+s];
    __syncthreads();
  }
  if (tid==0) atomicAdd(zsum, red[0]);
}

__global__ __launch_bounds__(256) void k_out3(const float* __restrict__ z, const unsigned* __restrict__ zmaxkey,
                                              const float* __restrict__ zsum, float* __restrict__ out, int n){
  int node = blockIdx.x*256 + threadIdx.x;
  if (node < n){
    float zmax = key2f(*zmaxkey);
    out[node] = expf(z[node]-zmax) / (*zsum);
  }
}

// ---------------- host launcher ----------------

extern "C" void kernel_launch(void* const* d_in, const int* in_sizes, int n_in,
                              void* d_out, int out_size, void* d_ws, size_t ws_size,
                              hipStream_t stream) {
  const float* x      = (const float*)d_in[0];
  const int*   ei     = (const int*)d_in[1];   // int64 in reference -> int32 on device per harness
  const float* A_in   = (const float*)d_in[2];
  const float* B_in   = (const float*)d_in[3];
  const float* A_conv = (const float*)d_in[4];
  const float* B_conv = (const float*)d_in[5];
  const float* W_out  = (const float*)d_in[6];
  const float* b_out  = (const float*)d_in[7];
  const int N = in_sizes[0] / 4;
  const int E = in_sizes[1] / 2;
  const int NROUNDS = 16;

  char* w = (char*)d_ws;
  size_t o = 0;
  auto alloc = [&](size_t bytes)->char* {
    char* p = w + o;
    o = (o + bytes + 15) & ~(size_t)15;
    return p;
  };
  // ---- zero-init control region (one memset) ----
  int*      deg8    = (int*)     alloc((size_t)NSEG*N*4);
  float*    colsum  = (float*)   alloc((size_t)NROUNDS*32*CSTR*4);
  unsigned* zmaxkey = (unsigned*)alloc(4);
  float*    zsum    = (float*)   alloc(4);
  size_t ctrl_bytes = o;
  // ---- rest ----
  int*   offs    = (int*)  alloc((size_t)(N+1)*4);
  int*   cursor  = (int*)  alloc((size_t)N*4);
  float* invdeg  = (float*)alloc((size_t)N*4);
  int    nb      = (N + 1023) / 1024;
  int*   bsum    = (int*)  alloc((size_t)nb*4);
  int*   bpre    = (int*)  alloc((size_t)nb*4);
  int*   csr     = (int*)  alloc((size_t)E*4);
  _Float16* uA   = (_Float16*)alloc((size_t)N*32*2);
  _Float16* uB   = (_Float16*)alloc((size_t)N*32*2);
  float* zbuf    = (float*)uB;  // uB free when k_out1 runs (final u lands in uA)
  (void)ws_size; (void)n_in; (void)out_size;

  hipMemsetAsync(d_ws, 0, ctrl_bytes, stream);

  int gridE = (E + 255) / 256;
  int gridN = (N + 255) / 256;
  int gridC = (N + 63) / 64;
  int bpg   = (E + CHUNK - 1) / CHUNK;

  // CSR build
  k_deg  <<<gridE, 256, 0, stream>>>(ei, deg8, E, N);
  k_scan1<<<nb, 1024, 0, stream>>>(deg8, offs, bsum, N);
  k_scan2<<<1, 64, 0, stream>>>(bsum, bpre, nb);
  k_scan3<<<gridN, 256, 0, stream>>>(offs, bpre, deg8, cursor, invdeg, N, E);
  k_fill <<<NGRP*bpg, 256, 0, stream>>>(ei, cursor, csr, E, N);

  // proj_in -> u0 = p
  k_in<<<gridN, 256, 0, stream>>>(x, uA, offs, csr, invdeg, A_in, B_in, N);

  // 16 conv rounds
  const float R17 = 1.0f/131072.0f;
  for (int r = 0; r < NROUNDS; r++){
    const float* Wa = A_conv + (size_t)r*32*32;
    const float* Wb = B_conv + (size_t)r*32*32;
    const float* cs_prev = (r == 0) ? nullptr : (colsum + (size_t)(r-1)*32*CSTR);
    float*       cs_next = colsum + (size_t)r*32*CSTR;
    float        Rs      = (r == 0) ? 1.0f : R17;
    const _Float16* ui = (r & 1) ? uB : uA;
    _Float16*       uo = (r & 1) ? uA : uB;
    k_conv<<<gridC, 256, 0, stream>>>(ui, uo, offs, csr, invdeg, Wa, Wb, cs_prev, Rs, cs_next, N);
  }

  // output layer (rc16 folded into W_out, f32 path)
  k_out1<<<gridN, 256, 0, stream>>>(uA, W_out, b_out, colsum + (size_t)(NROUNDS-1)*32*CSTR, zbuf, zmaxkey, N);
  k_out2<<<gridN, 256, 0, stream>>>(zbuf, zmaxkey, zsum, N);
  k_out3<<<gridN, 256, 0, stream>>>(zbuf, zmaxkey, zsum, (float*)d_out, N);
}

// Round 6
// 1178.841 us; speedup vs baseline: 2.3479x; 1.2544x over previous
//
#include <hip/hip_runtime.h>

#define NSEG 8
#define SEGSH 19 // k_deg: segment = edge >> 19
#define NGRP 8   // k_fill: dst-range groups; group = blockIdx%8 -> fixed XCD
#define CHUNK 2048
#define CSTR 64  // colsum element stride (256B) -> spread across L2 slices

typedef float    f2 __attribute__((ext_vector_type(2)));
typedef float    f4 __attribute__((ext_vector_type(4)));
typedef float    f8 __attribute__((ext_vector_type(8)));
typedef _Float16 h8 __attribute__((ext_vector_type(8)));

__device__ __forceinline__ unsigned f2key(float x){
  unsigned b = __float_as_uint(x);
  return (b & 0x80000000u) ? ~b : (b | 0x80000000u);
}
__device__ __forceinline__ float key2f(unsigned k){
  return (k & 0x80000000u) ? __uint_as_float(k ^ 0x80000000u) : __uint_as_float(~k);
}

// fp8 e4m3 HW decode: 4 bytes -> 4 floats
__device__ __forceinline__ f4 dec4(unsigned w){
  f2 a = __builtin_amdgcn_cvt_pk_f32_fp8((int)w, false);
  f2 b = __builtin_amdgcn_cvt_pk_f32_fp8((int)w, true);
  f4 r; r[0]=a[0]; r[1]=a[1]; r[2]=b[0]; r[3]=b[1];
  return r;
}
__device__ __forceinline__ f8 dec8(uint2 w){
  f4 lo = dec4(w.x), hi = dec4(w.y);
  f8 r;
  r[0]=lo[0]; r[1]=lo[1]; r[2]=lo[2]; r[3]=lo[3];
  r[4]=hi[0]; r[5]=hi[1]; r[6]=hi[2]; r[7]=hi[3];
  return r;
}

// ---------------- CSR build ----------------

__global__ void k_deg(const int* __restrict__ ei, int* __restrict__ deg8, int E, int n){
  int e = blockIdx.x*blockDim.x + threadIdx.x;
  if (e < E){
    int d = ei[E + e];
    int seg = e >> SEGSH; if (seg > NSEG-1) seg = NSEG-1;
    if ((unsigned)d < (unsigned)n) atomicAdd(&deg8[seg*n + d], 1);
  }
}

__global__ __launch_bounds__(1024) void k_scan1(const int* __restrict__ deg8, int* __restrict__ offs,
                                                int* __restrict__ bsum, int n){
  __shared__ int tmp[1024];
  int tid = threadIdx.x;
  int gid = blockIdx.x*1024 + tid;
  int v = 0;
  if (gid < n){
    #pragma unroll
    for (int s=0;s<NSEG;s++) v += deg8[s*n + gid];
  }
  tmp[tid] = v;
  __syncthreads();
  for (int o=1;o<1024;o<<=1){
    int t = (tid>=o) ? tmp[tid-o] : 0;
    __syncthreads();
    if (tid>=o) tmp[tid] += t;
    __syncthreads();
  }
  int inc = tmp[tid];
  if (gid < n) offs[gid] = inc - v;   // exclusive within chunk
  if (tid == 1023) bsum[blockIdx.x] = inc;
}

__global__ void k_scan2(const int* __restrict__ bsum, int* __restrict__ bpre, int nb){
  if (threadIdx.x==0 && blockIdx.x==0){
    int acc=0;
    for (int i=0;i<nb;i++){ bpre[i]=acc; acc+=bsum[i]; }
  }
}

__global__ void k_scan3(int* __restrict__ offs, const int* __restrict__ bpre,
                        const int* __restrict__ deg8, int* __restrict__ cursor,
                        float* __restrict__ invdeg, int n, int E){
  int gid = blockIdx.x*blockDim.x + threadIdx.x;
  if (gid < n){
    int base = offs[gid] + bpre[gid>>10];
    offs[gid] = base;
    cursor[gid] = base;
    int dtot = 0;
    #pragma unroll
    for (int s=0;s<NSEG;s++) dtot += deg8[s*n + gid];
    invdeg[gid] = (dtot>0) ? 1.0f/(float)dtot : 0.0f;  // 0 marks isolated node (ref avg = 0)
  }
  if (gid==0) offs[n] = E;
}

__global__ __launch_bounds__(256) void k_fill(const int* __restrict__ ei, int* __restrict__ cursor,
                                              int* __restrict__ csr, int E, int n){
  int g = blockIdx.x & (NGRP-1);
  int j = blockIdx.x >> 3;
  int span = (n + NGRP - 1) / NGRP;
  int lo = g * span;
  int base = j * CHUNK;
  if (base >= E) return;
  int end = base + CHUNK; if (end > E) end = E;
  for (int e = base + threadIdx.x; e < end; e += 256){
    int d = ei[E + e];
    if ((unsigned)(d - lo) < (unsigned)span && (unsigned)d < (unsigned)n){
      int s = ei[e];
      if ((unsigned)s < (unsigned)n){
        int pos = atomicAdd(&cursor[d], 1);
        if ((unsigned)pos < (unsigned)E) csr[pos] = s;
      }
    }
  }
}

// ---------------- proj_in: gather x[4] + (avg@A + x@B) + row softmax -> store p as fp8 (base 0) ----------------

__global__ __launch_bounds__(256) void k_in(const float* __restrict__ x, unsigned char* __restrict__ uout,
    const int* __restrict__ offs, const int* __restrict__ csr, const float* __restrict__ invdeg,
    const float* __restrict__ A, const float* __restrict__ B, int n){
  __shared__ float sA[128], sB[128];
  int tid = threadIdx.x;
  if (tid < 128){ sA[tid]=A[tid]; sB[tid]=B[tid]; }
  __syncthreads();
  int node = blockIdx.x*256 + tid;
  if (node >= n) return;
  float4 s = {0,0,0,0};
  int b0=offs[node], e0=offs[node+1];
  for (int k=b0;k<e0;k++){
    int sid = csr[k];
    float4 v = ((const float4*)x)[sid];
    s.x+=v.x; s.y+=v.y; s.z+=v.z; s.w+=v.w;
  }
  float idg = invdeg[node];
  s.x*=idg; s.y*=idg; s.z*=idg; s.w*=idg;
  float4 xr = ((const float4*)x)[node];
  float z[32];
  #pragma unroll
  for (int j=0;j<32;j++){
    z[j] = s.x*sA[j] + s.y*sA[32+j] + s.z*sA[64+j] + s.w*sA[96+j]
         + xr.x*sB[j] + xr.y*sB[32+j] + xr.z*sB[64+j] + xr.w*sB[96+j];
  }
  float m = z[0];
  #pragma unroll
  for (int j=1;j<32;j++) m = fmaxf(m,z[j]);
  float sum=0.0f;
  #pragma unroll
  for (int j=0;j<32;j++){ z[j]=expf(z[j]-m); sum+=z[j]; }
  float r = 1.0f/sum;
  unsigned pk[8];
  #pragma unroll
  for (int q=0;q<8;q++){
    int w0 = __builtin_amdgcn_cvt_pk_fp8_f32(z[4*q]*r,   z[4*q+1]*r, 0,  false);
    w0     = __builtin_amdgcn_cvt_pk_fp8_f32(z[4*q+2]*r, z[4*q+3]*r, w0, true);
    pk[q] = (unsigned)w0;
  }
  uint4* op = (uint4*)(uout + (size_t)node*32);
  op[0] = make_uint4(pk[0],pk[1],pk[2],pk[3]);
  op[1] = make_uint4(pk[4],pk[5],pk[6],pk[7]);
}

// ---------------- conv round (MFMA, fp8 state): wave = 16 nodes.
//  Storage: v = exp(p)-1 (fp8, base=1; round 0 input is p with base=0). u = v + base re-added
//  in f32 before fp16 MFMA fragments -> fp8 error only where elements are small.
//  Weights folded with rho = 2^17/(n + sum(v)) (fp16-safe), Rscale = 2^-17 in f32. ----------------

__global__ __launch_bounds__(256) void k_conv(
    const unsigned char* __restrict__ uin, unsigned char* __restrict__ uout,
    const int* __restrict__ offs, const int* __restrict__ csr,
    const float* __restrict__ invdeg,
    const float* __restrict__ Wa, const float* __restrict__ Wb,
    const float* __restrict__ cs_prev, float Rscale, float base,
    float* __restrict__ cs_next, int n){
  __shared__ float sWa[1024], sWb[1024];
  __shared__ float sCol[32];
  int tid = threadIdx.x;
  float rcf = 1.0f;
  if (cs_prev) rcf = 131072.0f / ((float)n + cs_prev[(tid>>3)*CSTR]);  // rho = 2^17/colsum
  ((f4*)sWa)[tid] = ((const f4*)Wa)[tid] * rcf;
  ((f4*)sWb)[tid] = ((const f4*)Wb)[tid] * rcf;
  if (tid < 32) sCol[tid] = 0.0f;
  __syncthreads();

  int lane = tid & 63;
  int wv   = tid >> 6;
  int q    = lane >> 4;         // k-chunk (A) / row-quad (C)
  int c    = lane & 15;         // gather node (A's m) / output column (B's n, C's col)
  int tile = blockIdx.x*64 + wv*16;
  int node = tile + c;
  bool gv = node < n;

  // B-fragments in registers: B[k][n], k = q*8+j, n = c (lo) / c+16 (hi)
  h8 waLo, waHi, wbLo, wbHi;
  #pragma unroll
  for (int j=0;j<8;j++){
    int k = q*8 + j;
    waLo[j] = (_Float16)sWa[k*32 + c];
    waHi[j] = (_Float16)sWa[k*32 + c + 16];
    wbLo[j] = (_Float16)sWb[k*32 + c];
    wbHi[j] = (_Float16)sWb[k*32 + c + 16];
  }

  // gather: mean of neighbor v rows (fp8 decode), this lane covers k-chunk q of node `tile+c`
  f8 a0 = {0,0,0,0,0,0,0,0}, a1 = {0,0,0,0,0,0,0,0};
  f8 a2 = {0,0,0,0,0,0,0,0}, a3 = {0,0,0,0,0,0,0,0};
  int b0 = gv ? offs[node]   : 0;
  int e0 = gv ? offs[node+1] : 0;
  const uint2* ub = (const uint2*)uin;
  int k = b0;
  for (; k+4<=e0; k+=4){
    int s0=csr[k], s1=csr[k+1], s2=csr[k+2], s3=csr[k+3];
    uint2 v0 = ub[(size_t)s0*4 + q];
    uint2 v1 = ub[(size_t)s1*4 + q];
    uint2 v2 = ub[(size_t)s2*4 + q];
    uint2 v3 = ub[(size_t)s3*4 + q];
    a0 += dec8(v0); a1 += dec8(v1); a2 += dec8(v2); a3 += dec8(v3);
  }
  for (; k<e0; k++) a0 += dec8(ub[(size_t)csr[k]*4 + q]);
  a0 = (a0 + a1) + (a2 + a3);
  float idg = gv ? invdeg[node] : 0.0f;
  float bavg = (idg != 0.0f) ? base : 0.0f;   // ref: isolated node -> avg = 0
  a0 = a0*idg + bavg;
  h8 afrag = __builtin_convertvector(a0, h8);
  f8 od = {0,0,0,0,0,0,0,0};
  if (gv) od = dec8(ub[(size_t)node*4 + q]) + base;
  h8 ofrag = __builtin_convertvector(od, h8);

  f4 z1 = {0,0,0,0}, z2 = {0,0,0,0};
  z1 = __builtin_amdgcn_mfma_f32_16x16x32_f16(ofrag, wbLo, z1, 0, 0, 0);
  z1 = __builtin_amdgcn_mfma_f32_16x16x32_f16(afrag, waLo, z1, 0, 0, 0);
  z2 = __builtin_amdgcn_mfma_f32_16x16x32_f16(ofrag, wbHi, z2, 0, 0, 0);
  z2 = __builtin_amdgcn_mfma_f32_16x16x32_f16(afrag, waHi, z2, 0, 0, 0);
  z1 *= Rscale; z2 *= Rscale;

  // C layout: row (node-in-tile) = q*4 + r, col = c (z1) / c+16 (z2)
  f4 mx, sm;
  #pragma unroll
  for (int r=0;r<4;r++) mx[r] = fmaxf(z1[r], z2[r]);
  #pragma unroll
  for (int s=1;s<16;s<<=1){
    #pragma unroll
    for (int r=0;r<4;r++) mx[r] = fmaxf(mx[r], __shfl_xor(mx[r], s));
  }
  #pragma unroll
  for (int r=0;r<4;r++){
    z1[r] = expf(z1[r]-mx[r]);
    z2[r] = expf(z2[r]-mx[r]);
    sm[r] = z1[r] + z2[r];
  }
  #pragma unroll
  for (int s=1;s<16;s<<=1){
    #pragma unroll
    for (int r=0;r<4;r++) sm[r] += __shfl_xor(sm[r], s);
  }
  float cs1 = 0.0f, cs2 = 0.0f;
  #pragma unroll
  for (int r=0;r<4;r++){
    float rs = 1.0f/sm[r];
    float v1 = expf(z1[r]*rs) - 1.0f;   // store v = u - 1, v in [0, 1.72] (fp8-friendly)
    float v2 = expf(z2[r]*rs) - 1.0f;
    int p1 = __builtin_amdgcn_cvt_pk_fp8_f32(v1, v1, 0, false);
    int p2 = __builtin_amdgcn_cvt_pk_fp8_f32(v2, v2, 0, false);
    f2 d1 = __builtin_amdgcn_cvt_pk_f32_fp8(p1, false);
    f2 d2 = __builtin_amdgcn_cvt_pk_f32_fp8(p2, false);
    int nd = tile + q*4 + r;
    if (nd < n){
      uout[(size_t)nd*32 + c]      = (unsigned char)(p1 & 0xff);
      uout[(size_t)nd*32 + c + 16] = (unsigned char)(p2 & 0xff);
      cs1 += d1[0];                 // colsum consistent with stored (rounded) v
      cs2 += d2[0];
    }
  }
  cs1 += __shfl_xor(cs1, 16); cs1 += __shfl_xor(cs1, 32);
  cs2 += __shfl_xor(cs2, 16); cs2 += __shfl_xor(cs2, 32);
  if (lane < 16){
    atomicAdd(&sCol[c],      cs1);
    atomicAdd(&sCol[c + 16], cs2);
  }
  __syncthreads();
  if (tid < 32) atomicAdd(&cs_next[tid*CSTR], sCol[tid]);
}

// ---------------- output layer: z = (1+v)@ (W/colsum) + b = b + sum(ws) + v@ws ----------------

__global__ __launch_bounds__(256) void k_out1(const unsigned char* __restrict__ u, const float* __restrict__ W,
    const float* __restrict__ bptr, const float* __restrict__ cs_last,
    float* __restrict__ z, unsigned* __restrict__ zmaxkey, int n){
  __shared__ float ws[32];
  __shared__ float red[256];
  int tid = threadIdx.x;
  if (tid < 32) ws[tid] = W[tid] * (1.0f / ((float)n + cs_last[tid*CSTR]));
  __syncthreads();
  float sws = 0.0f;
  #pragma unroll
  for (int j=0;j<32;j++) sws += ws[j];
  int node = blockIdx.x*256 + tid;
  float zz = -3.0e38f;
  if (node < n){
    float acc = bptr[0] + sws;
    const uint4* ur = (const uint4*)(u + (size_t)node*32);
    uint4 w0 = ur[0], w1 = ur[1];
    unsigned wd[8] = {w0.x,w0.y,w0.z,w0.w,w1.x,w1.y,w1.z,w1.w};
    #pragma unroll
    for (int q=0;q<8;q++){
      f4 a = dec4(wd[q]);
      f4 w = ((const f4*)ws)[q];
      acc += a[0]*w[0] + a[1]*w[1] + a[2]*w[2] + a[3]*w[3];
    }
    z[node]=acc; zz=acc;
  }
  red[tid]=zz; __syncthreads();
  for (int s=128;s>0;s>>=1){
    if (tid<s) red[tid]=fmaxf(red[tid],red[tid+s]);
    __syncthreads();
  }
  if (tid==0) atomicMax(zmaxkey, f2key(red[0]));
}

__global__ __launch_bounds__(256) void k_out2(const float* __restrict__ z, const unsigned* __restrict__ zmaxkey,
                                              float* __restrict__ zsum, int n){
  __shared__ float red[256];
  int tid = threadIdx.x;
  int node = blockIdx.x*256 + tid;
  float zmax = key2f(*zmaxkey);
  float v = (node<n) ? expf(z[node]-zmax) : 0.0f;
  red[tid]=v; __syncthreads();
  for (int s=128;s>0;s>>=1){
    if (tid<s) red[tid]+=red[tid+s];
    __syncthreads();
  }
  if (tid==0) atomicAdd(zsum, red[0]);
}

__global__ __launch_bounds__(256) void k_out3(const float* __restrict__ z, const unsigned* __restrict__ zmaxkey,
                                              const float* __restrict__ zsum, float* __restrict__ out, int n){
  int node = blockIdx.x*256 + threadIdx.x;
  if (node < n){
    float zmax = key2f(*zmaxkey);
    out[node] = expf(z[node]-zmax) / (*zsum);
  }
}

// ---------------- host launcher ----------------

extern "C" void kernel_launch(void* const* d_in, const int* in_sizes, int n_in,
                              void* d_out, int out_size, void* d_ws, size_t ws_size,
                              hipStream_t stream) {
  const float* x      = (const float*)d_in[0];
  const int*   ei     = (const int*)d_in[1];   // int64 in reference -> int32 on device per harness
  const float* A_in   = (const float*)d_in[2];
  const float* B_in   = (const float*)d_in[3];
  const float* A_conv = (const float*)d_in[4];
  const float* B_conv = (const float*)d_in[5];
  const float* W_out  = (const float*)d_in[6];
  const float* b_out  = (const float*)d_in[7];
  const int N = in_sizes[0] / 4;
  const int E = in_sizes[1] / 2;
  const int NROUNDS = 16;

  char* w = (char*)d_ws;
  size_t o = 0;
  auto alloc = [&](size_t bytes)->char* {
    char* p = w + o;
    o = (o + bytes + 15) & ~(size_t)15;
    return p;
  };
  // ---- zero-init control region (one memset) ----
  int*      deg8    = (int*)     alloc((size_t)NSEG*N*4);
  float*    colsum  = (float*)   alloc((size_t)NROUNDS*32*CSTR*4);
  unsigned* zmaxkey = (unsigned*)alloc(4);
  float*    zsum    = (float*)   alloc(4);
  size_t ctrl_bytes = o;
  // ---- rest ----
  int*   offs    = (int*)  alloc((size_t)(N+1)*4);
  int*   cursor  = (int*)  alloc((size_t)N*4);
  float* invdeg  = (float*)alloc((size_t)N*4);
  int    nb      = (N + 1023) / 1024;
  int*   bsum    = (int*)  alloc((size_t)nb*4);
  int*   bpre    = (int*)  alloc((size_t)nb*4);
  int*   csr     = (int*)  alloc((size_t)E*4);
  unsigned char* uA = (unsigned char*)alloc((size_t)N*32);
  unsigned char* uB = (unsigned char*)alloc((size_t)N*32);
  float* zbuf    = (float*)alloc((size_t)N*4);
  (void)ws_size; (void)n_in; (void)out_size;

  hipMemsetAsync(d_ws, 0, ctrl_bytes, stream);

  int gridE = (E + 255) / 256;
  int gridN = (N + 255) / 256;
  int gridC = (N + 63) / 64;
  int bpg   = (E + CHUNK - 1) / CHUNK;

  // CSR build
  k_deg  <<<gridE, 256, 0, stream>>>(ei, deg8, E, N);
  k_scan1<<<nb, 1024, 0, stream>>>(deg8, offs, bsum, N);
  k_scan2<<<1, 64, 0, stream>>>(bsum, bpre, nb);
  k_scan3<<<gridN, 256, 0, stream>>>(offs, bpre, deg8, cursor, invdeg, N, E);
  k_fill <<<NGRP*bpg, 256, 0, stream>>>(ei, cursor, csr, E, N);

  // proj_in -> p stored fp8 (base 0)
  k_in<<<gridN, 256, 0, stream>>>(x, uA, offs, csr, invdeg, A_in, B_in, N);

  // 16 conv rounds
  const float R17 = 1.0f/131072.0f;
  for (int r = 0; r < NROUNDS; r++){
    const float* Wa = A_conv + (size_t)r*32*32;
    const float* Wb = B_conv + (size_t)r*32*32;
    const float* cs_prev = (r == 0) ? nullptr : (colsum + (size_t)(r-1)*32*CSTR);
    float*       cs_next = colsum + (size_t)r*32*CSTR;
    float        Rs      = (r == 0) ? 1.0f : R17;
    float        base    = (r == 0) ? 0.0f : 1.0f;
    const unsigned char* ui = (r & 1) ? uB : uA;
    unsigned char*       uo = (r & 1) ? uA : uB;
    k_conv<<<gridC, 256, 0, stream>>>(ui, uo, offs, csr, invdeg, Wa, Wb, cs_prev, Rs, base, cs_next, N);
  }

  // output layer (colsum_16 = n + sum(v); folded into W_out)
  k_out1<<<gridN, 256, 0, stream>>>(uA, W_out, b_out, colsum + (size_t)(NROUNDS-1)*32*CSTR, zbuf, zmaxkey, N);
  k_out2<<<gridN, 256, 0, stream>>>(zbuf, zmaxkey, zsum, N);
  k_out3<<<gridN, 256, 0, stream>>>(zbuf, zmaxkey, zsum, (float*)d_out, N);
}